// Round 2
// baseline (1439.512 us; speedup 1.0000x reference)
//
#include <hip/hip_runtime.h>

#define SCAN_ITEMS 2048

__device__ __forceinline__ float bf2f(unsigned short h) {
  union { unsigned int u; float f; } c; c.u = ((unsigned int)h) << 16; return c.f;
}
__device__ __forceinline__ unsigned short f2bf(float f) {
  union { float f; unsigned int u; } c; c.f = f;
  unsigned int r = c.u + 0x7FFFu + ((c.u >> 16) & 1u);
  return (unsigned short)(r >> 16);
}

// ---------------- CSR build ----------------

__global__ __launch_bounds__(256) void hist_k(const int* __restrict__ dst,
                                              int* __restrict__ counts, int E) {
  int i = blockIdx.x * 256 + threadIdx.x;
  if (i < E) atomicAdd(&counts[dst[i]], 1);
}

__global__ __launch_bounds__(256) void scan_k1(const int* __restrict__ counts,
                                               int* __restrict__ aux, int N) {
  __shared__ int s[256];
  int b = blockIdx.x, tid = threadIdx.x;
  int base = b * SCAN_ITEMS;
  int sum = 0;
  for (int i = tid; i < SCAN_ITEMS; i += 256) {
    int idx = base + i;
    sum += (idx < N) ? counts[idx] : 0;
  }
  s[tid] = sum;
  __syncthreads();
  for (int off = 128; off > 0; off >>= 1) {
    if (tid < off) s[tid] += s[tid + off];
    __syncthreads();
  }
  if (tid == 0) aux[b] = s[0];
}

__global__ void scan_k2(int* aux, int nb) {
  if (threadIdx.x == 0 && blockIdx.x == 0) {
    int run = 0;
    for (int i = 0; i < nb; ++i) { int v = aux[i]; aux[i] = run; run += v; }
  }
}

__global__ __launch_bounds__(256) void scan_k3(const int* __restrict__ counts,
                                               const int* __restrict__ aux,
                                               int* __restrict__ row_start, int N) {
  __shared__ int s[256];
  int b = blockIdx.x, tid = threadIdx.x;
  int base = b * SCAN_ITEMS + tid * 8;
  int v[8];
  int sum = 0;
#pragma unroll
  for (int j = 0; j < 8; ++j) {
    int idx = base + j;
    v[j] = (idx < N) ? counts[idx] : 0;
    sum += v[j];
  }
  s[tid] = sum;
  __syncthreads();
  for (int off = 1; off < 256; off <<= 1) {
    int t = (tid >= off) ? s[tid - off] : 0;
    __syncthreads();
    s[tid] += t;
    __syncthreads();
  }
  int excl = (tid == 0) ? 0 : s[tid - 1];
  int run = aux[b] + excl;
#pragma unroll
  for (int j = 0; j < 8; ++j) {
    int idx = base + j;
    if (idx < N) row_start[idx] = run;
    run += v[j];
  }
}

__global__ __launch_bounds__(256) void scatter_k(const int* __restrict__ src,
                                                 const int* __restrict__ dst,
                                                 const float* __restrict__ w,
                                                 const int* __restrict__ row_start,
                                                 int* __restrict__ wptr,
                                                 int2* __restrict__ recs, int E) {
  int i = blockIdx.x * 256 + threadIdx.x;
  if (i >= E) return;
  int d = dst[i];
  int pos = row_start[d] + atomicAdd(&wptr[d], 1);
  int2 r;
  r.x = src[i];
  r.y = __float_as_int(w[i]);
  recs[pos] = r;
}

// ---------------- dense GEMM ----------------
// C[N,O](bf16) = A[N,K](fp32 or bf16) @ W[K,O](fp32); fp32 accumulate.
// Block tile 64 x O, BK=32, thread tile 4 x (O/16).

template <int K, int O, bool A_F32>
__global__ __launch_bounds__(256) void gemm_kernel(const void* __restrict__ Av,
                                                   const float* __restrict__ W,
                                                   unsigned short* __restrict__ C, int N) {
  constexpr int BM = 64;
  constexpr int BK = 32;
  constexpr int TM = 4;
  constexpr int TN = O / 16;
  __shared__ float As[BK][BM];
  __shared__ float Ws[BK][O];
  int tid = threadIdx.x;
  int tx = tid % 16;
  int ty = tid / 16;
  int rowBase = blockIdx.x * BM;
  float acc[TM][TN];
#pragma unroll
  for (int i = 0; i < TM; ++i)
#pragma unroll
    for (int j = 0; j < TN; ++j) acc[i][j] = 0.f;

  for (int k0 = 0; k0 < K; k0 += BK) {
    // A tile: 64 rows x 32 k; each thread loads 8 contiguous elements
    {
      int r = tid >> 2;
      int kc = (tid & 3) * 8;
      int gr = rowBase + r;
      if constexpr (A_F32) {
        const float* A = (const float*)Av;
        float4 v0 = make_float4(0.f, 0.f, 0.f, 0.f), v1 = v0;
        if (gr < N) {
          const float* ap = &A[(size_t)gr * K + k0 + kc];
          v0 = *reinterpret_cast<const float4*>(ap);
          v1 = *reinterpret_cast<const float4*>(ap + 4);
        }
        As[kc + 0][r] = v0.x; As[kc + 1][r] = v0.y;
        As[kc + 2][r] = v0.z; As[kc + 3][r] = v0.w;
        As[kc + 4][r] = v1.x; As[kc + 5][r] = v1.y;
        As[kc + 6][r] = v1.z; As[kc + 7][r] = v1.w;
      } else {
        const unsigned short* A = (const unsigned short*)Av;
        uint4 v = make_uint4(0u, 0u, 0u, 0u);
        if (gr < N) v = *reinterpret_cast<const uint4*>(&A[(size_t)gr * K + k0 + kc]);
        const unsigned short* pv = reinterpret_cast<const unsigned short*>(&v);
#pragma unroll
        for (int j = 0; j < 8; ++j) As[kc + j][r] = bf2f(pv[j]);
      }
    }
    // W tile (fp32): 32 k x O elements
    {
      constexpr int ELEMS = BK * O / 256;  // 16 / 8 / 4
      constexpr int NV = ELEMS / 4;
#pragma unroll
      for (int it = 0; it < NV; ++it) {
        int linear = (tid + it * 256) * 4;
        int kk = linear / O;
        int oo = linear % O;
        float4 v = *reinterpret_cast<const float4*>(&W[(size_t)(k0 + kk) * O + oo]);
        Ws[kk][oo + 0] = v.x; Ws[kk][oo + 1] = v.y;
        Ws[kk][oo + 2] = v.z; Ws[kk][oo + 3] = v.w;
      }
    }
    __syncthreads();
#pragma unroll
    for (int k = 0; k < BK; ++k) {
      float a[TM], w[TN];
#pragma unroll
      for (int i = 0; i < TM; ++i) a[i] = As[k][ty * TM + i];
#pragma unroll
      for (int j = 0; j < TN; ++j) w[j] = Ws[k][tx * TN + j];
#pragma unroll
      for (int i = 0; i < TM; ++i)
#pragma unroll
        for (int j = 0; j < TN; ++j) acc[i][j] += a[i] * w[j];
    }
    __syncthreads();
  }
#pragma unroll
  for (int i = 0; i < TM; ++i) {
    int gr = rowBase + ty * TM + i;
    if (gr >= N) continue;
#pragma unroll
    for (int j = 0; j < TN; j += 2) {
      unsigned int p = ((unsigned int)f2bf(acc[i][j + 1]) << 16) | f2bf(acc[i][j]);
      *reinterpret_cast<unsigned int*>(&C[(size_t)gr * O + tx * TN + j]) = p;
    }
  }
}

// ---------------- SpMM (CSR by dst, register accumulate) ----------------
// out[n,:] = sum_e w_e * sup[src_e,:]; optional ReLU; bf16 in/out.

template <int O, bool RELU>
__global__ __launch_bounds__(256) void spmm_kernel(const int2* __restrict__ recs,
                                                   const int* __restrict__ row_start,
                                                   const int* __restrict__ counts,
                                                   const unsigned short* __restrict__ sup,
                                                   unsigned short* __restrict__ hout, int N) {
  constexpr int SUBW = O / 2;
  constexpr int NPW = 256 / SUBW;
  int tid = threadIdx.x;
  int lane = tid % SUBW;
  int sub = tid / SUBW;
  int node = blockIdx.x * NPW + sub;
  if (node >= N) return;
  int start = row_start[node];
  int deg = counts[node];
  const unsigned int* supu = reinterpret_cast<const unsigned int*>(sup);
  float a0 = 0.f, a1 = 0.f;
  for (int i = 0; i < deg; ++i) {
    int2 rec = recs[start + i];
    float w = __int_as_float(rec.y);
    unsigned int v = supu[(size_t)rec.x * (O / 2) + lane];
    a0 += w * bf2f((unsigned short)(v & 0xFFFFu));
    a1 += w * bf2f((unsigned short)(v >> 16));
  }
  if (RELU) { a0 = fmaxf(a0, 0.f); a1 = fmaxf(a1, 0.f); }
  unsigned int p = ((unsigned int)f2bf(a1) << 16) | f2bf(a0);
  reinterpret_cast<unsigned int*>(hout)[(size_t)node * (O / 2) + lane] = p;
}

// Final layer: support [N,32] = [mu(16) | logvar(16)]. Writes z(=mu), mu,
// logvar into d_out as fp32, 3 * N * 16 floats flat in return order.
__global__ __launch_bounds__(256) void spmm_mulv_kernel(const int2* __restrict__ recs,
                                                        const int* __restrict__ row_start,
                                                        const int* __restrict__ counts,
                                                        const unsigned short* __restrict__ sup,
                                                        float* __restrict__ out, int N) {
  constexpr int SUBW = 16;  // 32 features / 2 per lane
  constexpr int NPW = 256 / SUBW;
  int tid = threadIdx.x;
  int lane = tid % SUBW;
  int sub = tid / SUBW;
  int node = blockIdx.x * NPW + sub;
  if (node >= N) return;
  int start = row_start[node];
  int deg = counts[node];
  const unsigned int* supu = reinterpret_cast<const unsigned int*>(sup);
  float a0 = 0.f, a1 = 0.f;
  for (int i = 0; i < deg; ++i) {
    int2 rec = recs[start + i];
    float w = __int_as_float(rec.y);
    unsigned int v = supu[(size_t)rec.x * 16 + lane];
    a0 += w * bf2f((unsigned short)(v & 0xFFFFu));
    a1 += w * bf2f((unsigned short)(v >> 16));
  }
  size_t nf = (size_t)N * 16;
  if (lane < 8) {
    float2 p = make_float2(a0, a1);
    *reinterpret_cast<float2*>(&out[(size_t)node * 16 + lane * 2]) = p;       // z
    *reinterpret_cast<float2*>(&out[nf + (size_t)node * 16 + lane * 2]) = p;  // mu
  } else {
    int l = lane - 8;
    *reinterpret_cast<float2*>(&out[2 * nf + (size_t)node * 16 + l * 2]) =
        make_float2(a0, a1);                                                  // logvar
  }
}

__global__ void packw_k(const float* __restrict__ Wmu,
                        const float* __restrict__ Wlv,
                        float* __restrict__ Wcat) {
  int i = blockIdx.x * 256 + threadIdx.x;
  if (i >= 32 * 32) return;
  int k = i / 32, o = i % 32;
  Wcat[i] = (o < 16) ? Wmu[k * 16 + o] : Wlv[k * 16 + (o - 16)];
}

// ---------------- launch ----------------

extern "C" void kernel_launch(void* const* d_in, const int* in_sizes, int n_in,
                              void* d_out, int out_size, void* d_ws, size_t ws_size,
                              hipStream_t stream) {
  const float* x    = (const float*)d_in[0];
  const int* esrc   = (const int*)d_in[1];
  const int* edst   = (const int*)d_in[2];
  const float* ew   = (const float*)d_in[3];
  const float* W1   = (const float*)d_in[4];
  const float* W2   = (const float*)d_in[5];
  const float* W3   = (const float*)d_in[6];
  const float* Wmu  = (const float*)d_in[7];
  const float* Wlv  = (const float*)d_in[8];
  float* out = (float*)d_out;
  int N = in_sizes[0] / 512;
  int E = in_sizes[1];

  char* p = (char*)d_ws;
  auto alloc = [&](size_t bytes) -> char* {
    char* r = p;
    p += (bytes + 255) & ~(size_t)255;
    return r;
  };
  int*  counts = (int*)alloc((size_t)N * 4);
  int*  wptr   = (int*)alloc((size_t)N * 4);
  int*  rowst  = (int*)alloc((size_t)N * 4);
  int*  aux    = (int*)alloc(4096);
  int2* recs   = (int2*)alloc((size_t)E * 8);
  unsigned short* bufA = (unsigned short*)alloc((size_t)N * 128 * 2);
  unsigned short* bufB = (unsigned short*)alloc((size_t)N * 128 * 2);
  float* Wcat = (float*)alloc(32 * 32 * 4);

  // CSR build (every launch; ws is re-poisoned each timed call)
  hipMemsetAsync(counts, 0, (size_t)N * 4, stream);
  hipMemsetAsync(wptr, 0, (size_t)N * 4, stream);
  hist_k<<<(E + 255) / 256, 256, 0, stream>>>(edst, counts, E);
  int nb = (N + SCAN_ITEMS - 1) / SCAN_ITEMS;
  scan_k1<<<nb, 256, 0, stream>>>(counts, aux, N);
  scan_k2<<<1, 64, 0, stream>>>(aux, nb);
  scan_k3<<<nb, 256, 0, stream>>>(counts, aux, rowst, N);
  scatter_k<<<(E + 255) / 256, 256, 0, stream>>>(esrc, edst, ew, rowst, wptr, recs, E);

  int gemmGrid = (N + 63) / 64;

  // layer 1: [N,512](f32) @ [512,128] -> spmm(relu) -> h1 (bf16) in bufB
  gemm_kernel<512, 128, true><<<gemmGrid, 256, 0, stream>>>(x, W1, bufA, N);
  spmm_kernel<128, true><<<(N + 3) / 4, 256, 0, stream>>>(recs, rowst, counts, bufA, bufB, N);

  // layer 2: [N,128]@[128,64] -> spmm(relu) -> h2 in bufB
  gemm_kernel<128, 64, false><<<gemmGrid, 256, 0, stream>>>(bufB, W2, bufA, N);
  spmm_kernel<64, true><<<(N + 7) / 8, 256, 0, stream>>>(recs, rowst, counts, bufA, bufB, N);

  // layer 3: [N,64]@[64,32] -> spmm(relu) -> h3 in bufB
  gemm_kernel<64, 32, false><<<gemmGrid, 256, 0, stream>>>(bufB, W3, bufA, N);
  spmm_kernel<32, true><<<(N + 15) / 16, 256, 0, stream>>>(recs, rowst, counts, bufA, bufB, N);

  // final: [N,32] @ [32,32(cat mu|lv)] -> spmm -> (z, mu, logvar) fp32
  packw_k<<<4, 256, 0, stream>>>(Wmu, Wlv, Wcat);
  gemm_kernel<32, 32, false><<<gemmGrid, 256, 0, stream>>>(bufB, Wcat, bufA, N);
  spmm_mulv_kernel<<<(N + 15) / 16, 256, 0, stream>>>(recs, rowst, counts, bufA, out, N);
}

// Round 3
// 1072.837 us; speedup vs baseline: 1.3418x; 1.3418x over previous
//
#include <hip/hip_runtime.h>

#define SCAN_ITEMS 2048

__device__ __forceinline__ float bf2f(unsigned short h) {
  union { unsigned int u; float f; } c; c.u = ((unsigned int)h) << 16; return c.f;
}
__device__ __forceinline__ unsigned short f2bf(float f) {
  union { float f; unsigned int u; } c; c.f = f;
  unsigned int r = c.u + 0x7FFFu + ((c.u >> 16) & 1u);
  return (unsigned short)(r >> 16);
}

// ---------------- CSR build ----------------

__global__ __launch_bounds__(256) void hist_k(const int* __restrict__ dst,
                                              int* __restrict__ counts, int E) {
  int i = blockIdx.x * 256 + threadIdx.x;
  if (i < E) atomicAdd(&counts[dst[i]], 1);
}

__global__ __launch_bounds__(256) void scan_k1(const int* __restrict__ counts,
                                               int* __restrict__ aux, int N) {
  __shared__ int s[256];
  int b = blockIdx.x, tid = threadIdx.x;
  int base = b * SCAN_ITEMS;
  int sum = 0;
  for (int i = tid; i < SCAN_ITEMS; i += 256) {
    int idx = base + i;
    sum += (idx < N) ? counts[idx] : 0;
  }
  s[tid] = sum;
  __syncthreads();
  for (int off = 128; off > 0; off >>= 1) {
    if (tid < off) s[tid] += s[tid + off];
    __syncthreads();
  }
  if (tid == 0) aux[b] = s[0];
}

__global__ void scan_k2(int* aux, int nb) {
  if (threadIdx.x == 0 && blockIdx.x == 0) {
    int run = 0;
    for (int i = 0; i < nb; ++i) { int v = aux[i]; aux[i] = run; run += v; }
  }
}

__global__ __launch_bounds__(256) void scan_k3(const int* __restrict__ counts,
                                               const int* __restrict__ aux,
                                               int* __restrict__ row_start, int N) {
  __shared__ int s[256];
  int b = blockIdx.x, tid = threadIdx.x;
  int base = b * SCAN_ITEMS + tid * 8;
  int v[8];
  int sum = 0;
#pragma unroll
  for (int j = 0; j < 8; ++j) {
    int idx = base + j;
    v[j] = (idx < N) ? counts[idx] : 0;
    sum += v[j];
  }
  s[tid] = sum;
  __syncthreads();
  for (int off = 1; off < 256; off <<= 1) {
    int t = (tid >= off) ? s[tid - off] : 0;
    __syncthreads();
    s[tid] += t;
    __syncthreads();
  }
  int excl = (tid == 0) ? 0 : s[tid - 1];
  int run = aux[b] + excl;
#pragma unroll
  for (int j = 0; j < 8; ++j) {
    int idx = base + j;
    if (idx < N) row_start[idx] = run;
    run += v[j];
  }
}

__global__ __launch_bounds__(256) void scatter_k(const int* __restrict__ src,
                                                 const int* __restrict__ dst,
                                                 const float* __restrict__ w,
                                                 const int* __restrict__ row_start,
                                                 int* __restrict__ wptr,
                                                 int2* __restrict__ recs, int E) {
  int i = blockIdx.x * 256 + threadIdx.x;
  if (i >= E) return;
  int d = dst[i];
  int pos = row_start[d] + atomicAdd(&wptr[d], 1);
  int2 r;
  r.x = src[i];
  r.y = __float_as_int(w[i]);
  recs[pos] = r;
}

// ---------------- layer-1 GEMM: [N,512](f32) @ [512,128](f32) -> bf16 ----
// 128x128 block tile, BK=32, 8x8 thread tile. 64 FMA per thread per k.

__global__ __launch_bounds__(256) void gemm1_kernel(const float* __restrict__ A,
                                                    const float* __restrict__ W,
                                                    unsigned short* __restrict__ C, int N) {
  constexpr int K = 512, O = 128, BM = 128, BK = 32;
  __shared__ float As[BK][BM];
  __shared__ float Ws[BK][O];
  int tid = threadIdx.x;
  int tx = tid % 16, ty = tid / 16;
  int rowBase = blockIdx.x * BM;
  float acc[8][8];
#pragma unroll
  for (int i = 0; i < 8; ++i)
#pragma unroll
    for (int j = 0; j < 8; ++j) acc[i][j] = 0.f;

  for (int k0 = 0; k0 < K; k0 += BK) {
    // A tile: 128 rows x 32 k; thread -> row tid/2, k-chunk (tid%2)*16 (4 float4)
    {
      int r = tid >> 1;
      int kc = (tid & 1) * 16;
      int gr = rowBase + r;
      float4 v[4];
      if (gr < N) {
        const float4* ap = reinterpret_cast<const float4*>(&A[(size_t)gr * K + k0 + kc]);
#pragma unroll
        for (int j = 0; j < 4; ++j) v[j] = ap[j];
      } else {
#pragma unroll
        for (int j = 0; j < 4; ++j) v[j] = make_float4(0.f, 0.f, 0.f, 0.f);
      }
#pragma unroll
      for (int j = 0; j < 4; ++j) {
        As[kc + j * 4 + 0][r] = v[j].x;
        As[kc + j * 4 + 1][r] = v[j].y;
        As[kc + j * 4 + 2][r] = v[j].z;
        As[kc + j * 4 + 3][r] = v[j].w;
      }
    }
    // W tile: 32 x 128 floats; 16 per thread (4 float4)
#pragma unroll
    for (int it = 0; it < 4; ++it) {
      int linear = (tid + it * 256) * 4;
      int kk = linear / O, oo = linear % O;
      float4 wv = *reinterpret_cast<const float4*>(&W[(size_t)(k0 + kk) * O + oo]);
      Ws[kk][oo + 0] = wv.x; Ws[kk][oo + 1] = wv.y;
      Ws[kk][oo + 2] = wv.z; Ws[kk][oo + 3] = wv.w;
    }
    __syncthreads();
#pragma unroll
    for (int k = 0; k < BK; ++k) {
      float a[8], w[8];
#pragma unroll
      for (int i = 0; i < 8; ++i) a[i] = As[k][ty * 8 + i];
#pragma unroll
      for (int j = 0; j < 8; ++j) w[j] = Ws[k][tx * 8 + j];
#pragma unroll
      for (int i = 0; i < 8; ++i)
#pragma unroll
        for (int j = 0; j < 8; ++j) acc[i][j] += a[i] * w[j];
    }
    __syncthreads();
  }
#pragma unroll
  for (int i = 0; i < 8; ++i) {
    int gr = rowBase + ty * 8 + i;
    if (gr >= N) continue;
#pragma unroll
    for (int j = 0; j < 8; j += 2) {
      unsigned int p = ((unsigned int)f2bf(acc[i][j + 1]) << 16) | f2bf(acc[i][j]);
      *reinterpret_cast<unsigned int*>(&C[(size_t)gr * O + tx * 8 + j]) = p;
    }
  }
}

// ---------------- small GEMM (layers 2-4): bf16 A, fp32 W -> bf16 --------

template <int K, int O>
__global__ __launch_bounds__(256) void gemm_kernel(const unsigned short* __restrict__ A,
                                                   const float* __restrict__ W,
                                                   unsigned short* __restrict__ C, int N) {
  constexpr int BM = 64;
  constexpr int BK = 32;
  constexpr int TM = 4;
  constexpr int TN = O / 16;
  __shared__ float As[BK][BM];
  __shared__ float Ws[BK][O];
  int tid = threadIdx.x;
  int tx = tid % 16;
  int ty = tid / 16;
  int rowBase = blockIdx.x * BM;
  float acc[TM][TN];
#pragma unroll
  for (int i = 0; i < TM; ++i)
#pragma unroll
    for (int j = 0; j < TN; ++j) acc[i][j] = 0.f;

  for (int k0 = 0; k0 < K; k0 += BK) {
    {
      int r = tid >> 2;
      int kc = (tid & 3) * 8;
      int gr = rowBase + r;
      uint4 v = make_uint4(0u, 0u, 0u, 0u);
      if (gr < N) v = *reinterpret_cast<const uint4*>(&A[(size_t)gr * K + k0 + kc]);
      const unsigned short* pv = reinterpret_cast<const unsigned short*>(&v);
#pragma unroll
      for (int j = 0; j < 8; ++j) As[kc + j][r] = bf2f(pv[j]);
    }
    {
      constexpr int ELEMS = BK * O / 256;  // 8 / 4
      constexpr int NV = ELEMS / 4;
#pragma unroll
      for (int it = 0; it < NV; ++it) {
        int linear = (tid + it * 256) * 4;
        int kk = linear / O;
        int oo = linear % O;
        float4 v = *reinterpret_cast<const float4*>(&W[(size_t)(k0 + kk) * O + oo]);
        Ws[kk][oo + 0] = v.x; Ws[kk][oo + 1] = v.y;
        Ws[kk][oo + 2] = v.z; Ws[kk][oo + 3] = v.w;
      }
    }
    __syncthreads();
#pragma unroll
    for (int k = 0; k < BK; ++k) {
      float a[TM], w[TN];
#pragma unroll
      for (int i = 0; i < TM; ++i) a[i] = As[k][ty * TM + i];
#pragma unroll
      for (int j = 0; j < TN; ++j) w[j] = Ws[k][tx * TN + j];
#pragma unroll
      for (int i = 0; i < TM; ++i)
#pragma unroll
        for (int j = 0; j < TN; ++j) acc[i][j] += a[i] * w[j];
    }
    __syncthreads();
  }
#pragma unroll
  for (int i = 0; i < TM; ++i) {
    int gr = rowBase + ty * TM + i;
    if (gr >= N) continue;
#pragma unroll
    for (int j = 0; j < TN; j += 2) {
      unsigned int p = ((unsigned int)f2bf(acc[i][j + 1]) << 16) | f2bf(acc[i][j]);
      *reinterpret_cast<unsigned int*>(&C[(size_t)gr * O + tx * TN + j]) = p;
    }
  }
}

// ---------------- SpMM (CSR by dst, register accumulate, 8x MLP) ---------

template <int O, bool RELU>
__global__ __launch_bounds__(256) void spmm_kernel(const int2* __restrict__ recs,
                                                   const int* __restrict__ row_start,
                                                   const int* __restrict__ counts,
                                                   const unsigned short* __restrict__ sup,
                                                   unsigned short* __restrict__ hout, int N) {
  constexpr int SUBW = O / 2;
  constexpr int NPW = 256 / SUBW;
  constexpr int U = 8;
  int tid = threadIdx.x;
  int lane = tid % SUBW;
  int sub = tid / SUBW;
  int node = blockIdx.x * NPW + sub;
  if (node >= N) return;
  int start = row_start[node];
  int deg = counts[node];
  const unsigned int* supu = reinterpret_cast<const unsigned int*>(sup);
  const int2* rp = recs + start;
  float a0 = 0.f, a1 = 0.f;
  int i = 0;
  for (; i + U <= deg; i += U) {
    int2 r[U];
#pragma unroll
    for (int j = 0; j < U; ++j) r[j] = rp[i + j];
    unsigned int v[U];
#pragma unroll
    for (int j = 0; j < U; ++j) v[j] = supu[(size_t)r[j].x * (O / 2) + lane];
#pragma unroll
    for (int j = 0; j < U; ++j) {
      float w = __int_as_float(r[j].y);
      a0 += w * bf2f((unsigned short)(v[j] & 0xFFFFu));
      a1 += w * bf2f((unsigned short)(v[j] >> 16));
    }
  }
  for (; i < deg; ++i) {
    int2 rec = rp[i];
    float w = __int_as_float(rec.y);
    unsigned int v = supu[(size_t)rec.x * (O / 2) + lane];
    a0 += w * bf2f((unsigned short)(v & 0xFFFFu));
    a1 += w * bf2f((unsigned short)(v >> 16));
  }
  if (RELU) { a0 = fmaxf(a0, 0.f); a1 = fmaxf(a1, 0.f); }
  unsigned int p = ((unsigned int)f2bf(a1) << 16) | f2bf(a0);
  reinterpret_cast<unsigned int*>(hout)[(size_t)node * (O / 2) + lane] = p;
}

// Final layer: support [N,32] = [mu(16) | logvar(16)]. Writes z(=mu), mu,
// logvar into d_out as fp32, 3 * N * 16 floats flat in return order.
__global__ __launch_bounds__(256) void spmm_mulv_kernel(const int2* __restrict__ recs,
                                                        const int* __restrict__ row_start,
                                                        const int* __restrict__ counts,
                                                        const unsigned short* __restrict__ sup,
                                                        float* __restrict__ out, int N) {
  constexpr int SUBW = 16;
  constexpr int NPW = 256 / SUBW;
  constexpr int U = 8;
  int tid = threadIdx.x;
  int lane = tid % SUBW;
  int sub = tid / SUBW;
  int node = blockIdx.x * NPW + sub;
  if (node >= N) return;
  int start = row_start[node];
  int deg = counts[node];
  const unsigned int* supu = reinterpret_cast<const unsigned int*>(sup);
  const int2* rp = recs + start;
  float a0 = 0.f, a1 = 0.f;
  int i = 0;
  for (; i + U <= deg; i += U) {
    int2 r[U];
#pragma unroll
    for (int j = 0; j < U; ++j) r[j] = rp[i + j];
    unsigned int v[U];
#pragma unroll
    for (int j = 0; j < U; ++j) v[j] = supu[(size_t)r[j].x * 16 + lane];
#pragma unroll
    for (int j = 0; j < U; ++j) {
      float w = __int_as_float(r[j].y);
      a0 += w * bf2f((unsigned short)(v[j] & 0xFFFFu));
      a1 += w * bf2f((unsigned short)(v[j] >> 16));
    }
  }
  for (; i < deg; ++i) {
    int2 rec = rp[i];
    float w = __int_as_float(rec.y);
    unsigned int v = supu[(size_t)rec.x * 16 + lane];
    a0 += w * bf2f((unsigned short)(v & 0xFFFFu));
    a1 += w * bf2f((unsigned short)(v >> 16));
  }
  size_t nf = (size_t)N * 16;
  if (lane < 8) {
    float2 p = make_float2(a0, a1);
    *reinterpret_cast<float2*>(&out[(size_t)node * 16 + lane * 2]) = p;       // z
    *reinterpret_cast<float2*>(&out[nf + (size_t)node * 16 + lane * 2]) = p;  // mu
  } else {
    int l = lane - 8;
    *reinterpret_cast<float2*>(&out[2 * nf + (size_t)node * 16 + l * 2]) =
        make_float2(a0, a1);                                                  // logvar
  }
}

__global__ void packw_k(const float* __restrict__ Wmu,
                        const float* __restrict__ Wlv,
                        float* __restrict__ Wcat) {
  int i = blockIdx.x * 256 + threadIdx.x;
  if (i >= 32 * 32) return;
  int k = i / 32, o = i % 32;
  Wcat[i] = (o < 16) ? Wmu[k * 16 + o] : Wlv[k * 16 + (o - 16)];
}

// ---------------- launch ----------------

extern "C" void kernel_launch(void* const* d_in, const int* in_sizes, int n_in,
                              void* d_out, int out_size, void* d_ws, size_t ws_size,
                              hipStream_t stream) {
  const float* x    = (const float*)d_in[0];
  const int* esrc   = (const int*)d_in[1];
  const int* edst   = (const int*)d_in[2];
  const float* ew   = (const float*)d_in[3];
  const float* W1   = (const float*)d_in[4];
  const float* W2   = (const float*)d_in[5];
  const float* W3   = (const float*)d_in[6];
  const float* Wmu  = (const float*)d_in[7];
  const float* Wlv  = (const float*)d_in[8];
  float* out = (float*)d_out;
  int N = in_sizes[0] / 512;
  int E = in_sizes[1];

  char* p = (char*)d_ws;
  auto alloc = [&](size_t bytes) -> char* {
    char* r = p;
    p += (bytes + 255) & ~(size_t)255;
    return r;
  };
  int*  counts = (int*)alloc((size_t)N * 4);
  int*  wptr   = (int*)alloc((size_t)N * 4);
  int*  rowst  = (int*)alloc((size_t)N * 4);
  int*  aux    = (int*)alloc(4096);
  int2* recs   = (int2*)alloc((size_t)E * 8);
  unsigned short* bufA = (unsigned short*)alloc((size_t)N * 128 * 2);
  unsigned short* bufB = (unsigned short*)alloc((size_t)N * 128 * 2);
  float* Wcat = (float*)alloc(32 * 32 * 4);

  // CSR build (every launch; ws is re-poisoned each timed call)
  hipMemsetAsync(counts, 0, (size_t)N * 4, stream);
  hipMemsetAsync(wptr, 0, (size_t)N * 4, stream);
  hist_k<<<(E + 255) / 256, 256, 0, stream>>>(edst, counts, E);
  int nb = (N + SCAN_ITEMS - 1) / SCAN_ITEMS;
  scan_k1<<<nb, 256, 0, stream>>>(counts, aux, N);
  scan_k2<<<1, 64, 0, stream>>>(aux, nb);
  scan_k3<<<nb, 256, 0, stream>>>(counts, aux, rowst, N);
  scatter_k<<<(E + 255) / 256, 256, 0, stream>>>(esrc, edst, ew, rowst, wptr, recs, E);

  // layer 1: [N,512](f32) @ [512,128] -> spmm(relu) -> h1 (bf16) in bufB
  gemm1_kernel<<<(N + 127) / 128, 256, 0, stream>>>(x, W1, bufA, N);
  spmm_kernel<128, true><<<(N + 3) / 4, 256, 0, stream>>>(recs, rowst, counts, bufA, bufB, N);

  int gemmGrid = (N + 63) / 64;

  // layer 2: [N,128]@[128,64] -> spmm(relu) -> h2 in bufB
  gemm_kernel<128, 64><<<gemmGrid, 256, 0, stream>>>(bufB, W2, bufA, N);
  spmm_kernel<64, true><<<(N + 7) / 8, 256, 0, stream>>>(recs, rowst, counts, bufA, bufB, N);

  // layer 3: [N,64]@[64,32] -> spmm(relu) -> h3 in bufB
  gemm_kernel<64, 32><<<gemmGrid, 256, 0, stream>>>(bufB, W3, bufA, N);
  spmm_kernel<32, true><<<(N + 15) / 16, 256, 0, stream>>>(recs, rowst, counts, bufA, bufB, N);

  // final: [N,32] @ [32,32(cat mu|lv)] -> spmm -> (z, mu, logvar) fp32
  packw_k<<<4, 256, 0, stream>>>(Wmu, Wlv, Wcat);
  gemm_kernel<32, 32><<<gemmGrid, 256, 0, stream>>>(bufB, Wcat, bufA, N);
  spmm_mulv_kernel<<<(N + 15) / 16, 256, 0, stream>>>(recs, rowst, counts, bufA, out, N);
}

// Round 4
// 980.329 us; speedup vs baseline: 1.4684x; 1.0944x over previous
//
#include <hip/hip_runtime.h>

#define SCAN_ITEMS 2048

typedef __attribute__((ext_vector_type(4))) float floatx4;
typedef __attribute__((ext_vector_type(8))) short bf16x8;

__device__ __forceinline__ float bf2f(unsigned short h) {
  union { unsigned int u; float f; } c; c.u = ((unsigned int)h) << 16; return c.f;
}
__device__ __forceinline__ unsigned short f2bf(float f) {
  union { float f; unsigned int u; } c; c.f = f;
  unsigned int r = c.u + 0x7FFFu + ((c.u >> 16) & 1u);
  return (unsigned short)(r >> 16);
}

// ---------------- CSR build ----------------

__global__ __launch_bounds__(256) void hist_k(const int* __restrict__ dst,
                                              int* __restrict__ counts, int E) {
  int i = blockIdx.x * 256 + threadIdx.x;
  if (i < E) atomicAdd(&counts[dst[i]], 1);
}

__global__ __launch_bounds__(256) void scan_k1(const int* __restrict__ counts,
                                               int* __restrict__ aux, int N) {
  __shared__ int s[256];
  int b = blockIdx.x, tid = threadIdx.x;
  int base = b * SCAN_ITEMS;
  int sum = 0;
  for (int i = tid; i < SCAN_ITEMS; i += 256) {
    int idx = base + i;
    sum += (idx < N) ? counts[idx] : 0;
  }
  s[tid] = sum;
  __syncthreads();
  for (int off = 128; off > 0; off >>= 1) {
    if (tid < off) s[tid] += s[tid + off];
    __syncthreads();
  }
  if (tid == 0) aux[b] = s[0];
}

__global__ void scan_k2(int* aux, int nb) {
  if (threadIdx.x == 0 && blockIdx.x == 0) {
    int run = 0;
    for (int i = 0; i < nb; ++i) { int v = aux[i]; aux[i] = run; run += v; }
  }
}

__global__ __launch_bounds__(256) void scan_k3(const int* __restrict__ counts,
                                               const int* __restrict__ aux,
                                               int* __restrict__ row_start, int N) {
  __shared__ int s[256];
  int b = blockIdx.x, tid = threadIdx.x;
  int base = b * SCAN_ITEMS + tid * 8;
  int v[8];
  int sum = 0;
#pragma unroll
  for (int j = 0; j < 8; ++j) {
    int idx = base + j;
    v[j] = (idx < N) ? counts[idx] : 0;
    sum += v[j];
  }
  s[tid] = sum;
  __syncthreads();
  for (int off = 1; off < 256; off <<= 1) {
    int t = (tid >= off) ? s[tid - off] : 0;
    __syncthreads();
    s[tid] += t;
    __syncthreads();
  }
  int excl = (tid == 0) ? 0 : s[tid - 1];
  int run = aux[b] + excl;
#pragma unroll
  for (int j = 0; j < 8; ++j) {
    int idx = base + j;
    if (idx < N) row_start[idx] = run;
    run += v[j];
  }
}

__global__ __launch_bounds__(256) void scatter_k(const int* __restrict__ src,
                                                 const int* __restrict__ dst,
                                                 const float* __restrict__ w,
                                                 const int* __restrict__ row_start,
                                                 int* __restrict__ wptr,
                                                 int2* __restrict__ recs, int E) {
  int i = blockIdx.x * 256 + threadIdx.x;
  if (i >= E) return;
  int d = dst[i];
  int pos = row_start[d] + atomicAdd(&wptr[d], 1);
  int2 r;
  r.x = src[i];
  r.y = __float_as_int(w[i]);
  recs[pos] = r;
}

// ---------------- W1 transpose + bf16 convert: [512,128]f32 -> [128,512]bf16

__global__ __launch_bounds__(256) void tw1_k(const float* __restrict__ W1,
                                             unsigned short* __restrict__ W1t) {
  int i = blockIdx.x * 256 + threadIdx.x;  // 65536 elements
  if (i >= 512 * 128) return;
  int k = i >> 7, n = i & 127;
  W1t[n * 512 + k] = f2bf(W1[i]);
}

// ---------------- layer-1 GEMM via MFMA --------------------------------
// C[N,128](bf16) = x[N,512](f32, cvt->bf16) @ W1[512,128]
// 128x128 block tile, BK=64, 4 waves, each wave owns a 32-col strip.
// MFMA 16x16x32 bf16. A lane layout: m=lane&15, k=(lane>>4)*8+j.
// B lane layout: n=lane&15, k=(lane>>4)*8+j. D: col=lane&15, row=(lane>>4)*4+p.

__global__ __launch_bounds__(256) void gemm1_mfma(const float* __restrict__ A,
                                                  const unsigned short* __restrict__ W1t,
                                                  unsigned short* __restrict__ C, int N) {
  constexpr int K = 512, BK = 64, PAD = 72;
  __shared__ short As[128 * PAD];  // [row][k] bf16, padded 64->72
  __shared__ short Bs[128 * PAD];  // [n][k]   bf16, padded
  int tid = threadIdx.x;
  int lane = tid & 63;
  int w = tid >> 6;          // wave id 0..3
  int m0 = lane & 15;
  int kq = lane >> 4;        // 0..3
  int rowBase = blockIdx.x * 128;

  floatx4 acc[8][2];
#pragma unroll
  for (int i = 0; i < 8; ++i)
#pragma unroll
    for (int j = 0; j < 2; ++j) acc[i][j] = (floatx4)0.f;

  for (int k0 = 0; k0 < K; k0 += BK) {
    // stage A: 128 rows x 64 k fp32 -> bf16 LDS. linear float4 mapping,
    // coalesced: consecutive tid -> consecutive 16B within a row.
#pragma unroll
    for (int it = 0; it < 8; ++it) {
      int f = (tid + it * 256) * 4;   // float index in 128x64 tile
      int r = f >> 6;
      int kk = f & 63;
      int gr = rowBase + r;
      float4 v = make_float4(0.f, 0.f, 0.f, 0.f);
      if (gr < N) v = *reinterpret_cast<const float4*>(&A[(size_t)gr * K + k0 + kk]);
      ushort2 p0 = make_ushort2(f2bf(v.x), f2bf(v.y));
      ushort2 p1 = make_ushort2(f2bf(v.z), f2bf(v.w));
      unsigned int u0 = ((unsigned int)p0.y << 16) | p0.x;
      unsigned int u1 = ((unsigned int)p1.y << 16) | p1.x;
      *reinterpret_cast<uint2*>(&As[r * PAD + kk]) = make_uint2(u0, u1);
    }
    // stage B: W1t rows [n][k0..k0+63] -> Bs
#pragma unroll
    for (int it = 0; it < 4; ++it) {
      int t2 = tid + it * 256;
      int n = t2 >> 3;
      int kc = (t2 & 7) * 8;
      uint4 v = *reinterpret_cast<const uint4*>(&W1t[(size_t)n * 512 + k0 + kc]);
      *reinterpret_cast<uint4*>(&Bs[n * PAD + kc]) = v;
    }
    __syncthreads();
#pragma unroll
    for (int kb = 0; kb < 2; ++kb) {
      int kbase = kb * 32 + kq * 8;
      bf16x8 a[8], b[2];
#pragma unroll
      for (int mi = 0; mi < 8; ++mi)
        a[mi] = *reinterpret_cast<const bf16x8*>(&As[(mi * 16 + m0) * PAD + kbase]);
#pragma unroll
      for (int jn = 0; jn < 2; ++jn)
        b[jn] = *reinterpret_cast<const bf16x8*>(&Bs[(w * 32 + jn * 16 + m0) * PAD + kbase]);
#pragma unroll
      for (int mi = 0; mi < 8; ++mi)
#pragma unroll
        for (int jn = 0; jn < 2; ++jn)
          acc[mi][jn] = __builtin_amdgcn_mfma_f32_16x16x32_bf16(a[mi], b[jn], acc[mi][jn], 0, 0, 0);
    }
    __syncthreads();
  }
  // epilogue: D col = lane&15, row = (lane>>4)*4 + p
#pragma unroll
  for (int mi = 0; mi < 8; ++mi) {
#pragma unroll
    for (int jn = 0; jn < 2; ++jn) {
      int gc = w * 32 + jn * 16 + m0;
#pragma unroll
      for (int p = 0; p < 4; ++p) {
        int gr = rowBase + mi * 16 + kq * 4 + p;
        if (gr < N) C[(size_t)gr * 128 + gc] = f2bf(acc[mi][jn][p]);
      }
    }
  }
}

// ---------------- small GEMM (layers 2-4): bf16 A, fp32 W -> bf16 --------

template <int K, int O>
__global__ __launch_bounds__(256) void gemm_kernel(const unsigned short* __restrict__ A,
                                                   const float* __restrict__ W,
                                                   unsigned short* __restrict__ C, int N) {
  constexpr int BM = 64;
  constexpr int BK = 32;
  constexpr int TM = 4;
  constexpr int TN = O / 16;
  __shared__ float As[BK][BM];
  __shared__ float Ws[BK][O];
  int tid = threadIdx.x;
  int tx = tid % 16;
  int ty = tid / 16;
  int rowBase = blockIdx.x * BM;
  float acc[TM][TN];
#pragma unroll
  for (int i = 0; i < TM; ++i)
#pragma unroll
    for (int j = 0; j < TN; ++j) acc[i][j] = 0.f;

  for (int k0 = 0; k0 < K; k0 += BK) {
    {
      int r = tid >> 2;
      int kc = (tid & 3) * 8;
      int gr = rowBase + r;
      uint4 v = make_uint4(0u, 0u, 0u, 0u);
      if (gr < N) v = *reinterpret_cast<const uint4*>(&A[(size_t)gr * K + k0 + kc]);
      const unsigned short* pv = reinterpret_cast<const unsigned short*>(&v);
#pragma unroll
      for (int j = 0; j < 8; ++j) As[kc + j][r] = bf2f(pv[j]);
    }
    {
      constexpr int ELEMS = BK * O / 256;  // 8 / 4
      constexpr int NV = ELEMS / 4;
#pragma unroll
      for (int it = 0; it < NV; ++it) {
        int linear = (tid + it * 256) * 4;
        int kk = linear / O;
        int oo = linear % O;
        float4 v = *reinterpret_cast<const float4*>(&W[(size_t)(k0 + kk) * O + oo]);
        Ws[kk][oo + 0] = v.x; Ws[kk][oo + 1] = v.y;
        Ws[kk][oo + 2] = v.z; Ws[kk][oo + 3] = v.w;
      }
    }
    __syncthreads();
#pragma unroll
    for (int k = 0; k < BK; ++k) {
      float a[TM], w[TN];
#pragma unroll
      for (int i = 0; i < TM; ++i) a[i] = As[k][ty * TM + i];
#pragma unroll
      for (int j = 0; j < TN; ++j) w[j] = Ws[k][tx * TN + j];
#pragma unroll
      for (int i = 0; i < TM; ++i)
#pragma unroll
        for (int j = 0; j < TN; ++j) acc[i][j] += a[i] * w[j];
    }
    __syncthreads();
  }
#pragma unroll
  for (int i = 0; i < TM; ++i) {
    int gr = rowBase + ty * TM + i;
    if (gr >= N) continue;
#pragma unroll
    for (int j = 0; j < TN; j += 2) {
      unsigned int p = ((unsigned int)f2bf(acc[i][j + 1]) << 16) | f2bf(acc[i][j]);
      *reinterpret_cast<unsigned int*>(&C[(size_t)gr * O + tx * TN + j]) = p;
    }
  }
}

// ---------------- SpMM (CSR by dst, register accumulate, 8x MLP) ---------

template <int O, bool RELU>
__global__ __launch_bounds__(256) void spmm_kernel(const int2* __restrict__ recs,
                                                   const int* __restrict__ row_start,
                                                   const int* __restrict__ counts,
                                                   const unsigned short* __restrict__ sup,
                                                   unsigned short* __restrict__ hout, int N) {
  constexpr int SUBW = O / 2;
  constexpr int NPW = 256 / SUBW;
  constexpr int U = 8;
  int tid = threadIdx.x;
  int lane = tid % SUBW;
  int sub = tid / SUBW;
  int node = blockIdx.x * NPW + sub;
  if (node >= N) return;
  int start = row_start[node];
  int deg = counts[node];
  const unsigned int* supu = reinterpret_cast<const unsigned int*>(sup);
  const int2* rp = recs + start;
  float a0 = 0.f, a1 = 0.f;
  int i = 0;
  for (; i + U <= deg; i += U) {
    int2 r[U];
#pragma unroll
    for (int j = 0; j < U; ++j) r[j] = rp[i + j];
    unsigned int v[U];
#pragma unroll
    for (int j = 0; j < U; ++j) v[j] = supu[(size_t)r[j].x * (O / 2) + lane];
#pragma unroll
    for (int j = 0; j < U; ++j) {
      float w = __int_as_float(r[j].y);
      a0 += w * bf2f((unsigned short)(v[j] & 0xFFFFu));
      a1 += w * bf2f((unsigned short)(v[j] >> 16));
    }
  }
  for (; i < deg; ++i) {
    int2 rec = rp[i];
    float w = __int_as_float(rec.y);
    unsigned int v = supu[(size_t)rec.x * (O / 2) + lane];
    a0 += w * bf2f((unsigned short)(v & 0xFFFFu));
    a1 += w * bf2f((unsigned short)(v >> 16));
  }
  if (RELU) { a0 = fmaxf(a0, 0.f); a1 = fmaxf(a1, 0.f); }
  unsigned int p = ((unsigned int)f2bf(a1) << 16) | f2bf(a0);
  reinterpret_cast<unsigned int*>(hout)[(size_t)node * (O / 2) + lane] = p;
}

// Final layer: support [N,32] = [mu(16) | logvar(16)]. Writes z(=mu), mu,
// logvar into d_out as fp32, 3 * N * 16 floats flat in return order.
__global__ __launch_bounds__(256) void spmm_mulv_kernel(const int2* __restrict__ recs,
                                                        const int* __restrict__ row_start,
                                                        const int* __restrict__ counts,
                                                        const unsigned short* __restrict__ sup,
                                                        float* __restrict__ out, int N) {
  constexpr int SUBW = 16;
  constexpr int NPW = 256 / SUBW;
  constexpr int U = 8;
  int tid = threadIdx.x;
  int lane = tid % SUBW;
  int sub = tid / SUBW;
  int node = blockIdx.x * NPW + sub;
  if (node >= N) return;
  int start = row_start[node];
  int deg = counts[node];
  const unsigned int* supu = reinterpret_cast<const unsigned int*>(sup);
  const int2* rp = recs + start;
  float a0 = 0.f, a1 = 0.f;
  int i = 0;
  for (; i + U <= deg; i += U) {
    int2 r[U];
#pragma unroll
    for (int j = 0; j < U; ++j) r[j] = rp[i + j];
    unsigned int v[U];
#pragma unroll
    for (int j = 0; j < U; ++j) v[j] = supu[(size_t)r[j].x * 16 + lane];
#pragma unroll
    for (int j = 0; j < U; ++j) {
      float w = __int_as_float(r[j].y);
      a0 += w * bf2f((unsigned short)(v[j] & 0xFFFFu));
      a1 += w * bf2f((unsigned short)(v[j] >> 16));
    }
  }
  for (; i < deg; ++i) {
    int2 rec = rp[i];
    float w = __int_as_float(rec.y);
    unsigned int v = supu[(size_t)rec.x * 16 + lane];
    a0 += w * bf2f((unsigned short)(v & 0xFFFFu));
    a1 += w * bf2f((unsigned short)(v >> 16));
  }
  size_t nf = (size_t)N * 16;
  if (lane < 8) {
    float2 p = make_float2(a0, a1);
    *reinterpret_cast<float2*>(&out[(size_t)node * 16 + lane * 2]) = p;       // z
    *reinterpret_cast<float2*>(&out[nf + (size_t)node * 16 + lane * 2]) = p;  // mu
  } else {
    int l = lane - 8;
    *reinterpret_cast<float2*>(&out[2 * nf + (size_t)node * 16 + l * 2]) =
        make_float2(a0, a1);                                                  // logvar
  }
}

__global__ void packw_k(const float* __restrict__ Wmu,
                        const float* __restrict__ Wlv,
                        float* __restrict__ Wcat) {
  int i = blockIdx.x * 256 + threadIdx.x;
  if (i >= 32 * 32) return;
  int k = i / 32, o = i % 32;
  Wcat[i] = (o < 16) ? Wmu[k * 16 + o] : Wlv[k * 16 + (o - 16)];
}

// ---------------- launch ----------------

extern "C" void kernel_launch(void* const* d_in, const int* in_sizes, int n_in,
                              void* d_out, int out_size, void* d_ws, size_t ws_size,
                              hipStream_t stream) {
  const float* x    = (const float*)d_in[0];
  const int* esrc   = (const int*)d_in[1];
  const int* edst   = (const int*)d_in[2];
  const float* ew   = (const float*)d_in[3];
  const float* W1   = (const float*)d_in[4];
  const float* W2   = (const float*)d_in[5];
  const float* W3   = (const float*)d_in[6];
  const float* Wmu  = (const float*)d_in[7];
  const float* Wlv  = (const float*)d_in[8];
  float* out = (float*)d_out;
  int N = in_sizes[0] / 512;
  int E = in_sizes[1];

  char* p = (char*)d_ws;
  auto alloc = [&](size_t bytes) -> char* {
    char* r = p;
    p += (bytes + 255) & ~(size_t)255;
    return r;
  };
  int*  counts = (int*)alloc((size_t)N * 4);
  int*  wptr   = (int*)alloc((size_t)N * 4);
  int*  rowst  = (int*)alloc((size_t)N * 4);
  int*  aux    = (int*)alloc(4096);
  int2* recs   = (int2*)alloc((size_t)E * 8);
  unsigned short* bufA = (unsigned short*)alloc((size_t)N * 128 * 2);
  unsigned short* bufB = (unsigned short*)alloc((size_t)N * 128 * 2);
  unsigned short* W1t  = (unsigned short*)alloc(512 * 128 * 2);
  float* Wcat = (float*)alloc(32 * 32 * 4);

  // CSR build (every launch; ws is re-poisoned each timed call)
  hipMemsetAsync(counts, 0, (size_t)N * 4, stream);
  hipMemsetAsync(wptr, 0, (size_t)N * 4, stream);
  hist_k<<<(E + 255) / 256, 256, 0, stream>>>(edst, counts, E);
  int nb = (N + SCAN_ITEMS - 1) / SCAN_ITEMS;
  scan_k1<<<nb, 256, 0, stream>>>(counts, aux, N);
  scan_k2<<<1, 64, 0, stream>>>(aux, nb);
  scan_k3<<<nb, 256, 0, stream>>>(counts, aux, rowst, N);
  scatter_k<<<(E + 255) / 256, 256, 0, stream>>>(esrc, edst, ew, rowst, wptr, recs, E);

  // layer 1: MFMA GEMM [N,512](f32->bf16) @ W1 -> spmm(relu) -> h1 in bufB
  tw1_k<<<256, 256, 0, stream>>>(W1, W1t);
  gemm1_mfma<<<(N + 127) / 128, 256, 0, stream>>>(x, W1t, bufA, N);
  spmm_kernel<128, true><<<(N + 3) / 4, 256, 0, stream>>>(recs, rowst, counts, bufA, bufB, N);

  int gemmGrid = (N + 63) / 64;

  // layer 2: [N,128]@[128,64] -> spmm(relu) -> h2 in bufB
  gemm_kernel<128, 64><<<gemmGrid, 256, 0, stream>>>(bufB, W2, bufA, N);
  spmm_kernel<64, true><<<(N + 7) / 8, 256, 0, stream>>>(recs, rowst, counts, bufA, bufB, N);

  // layer 3: [N,64]@[64,32] -> spmm(relu) -> h3 in bufB
  gemm_kernel<64, 32><<<gemmGrid, 256, 0, stream>>>(bufB, W3, bufA, N);
  spmm_kernel<32, true><<<(N + 15) / 16, 256, 0, stream>>>(recs, rowst, counts, bufA, bufB, N);

  // final: [N,32] @ [32,32(cat mu|lv)] -> spmm -> (z, mu, logvar) fp32
  packw_k<<<4, 256, 0, stream>>>(Wmu, Wlv, Wcat);
  gemm_kernel<32, 32><<<gemmGrid, 256, 0, stream>>>(bufB, Wcat, bufA, N);
  spmm_mulv_kernel<<<(N + 15) / 16, 256, 0, stream>>>(recs, rowst, counts, bufA, out, N);
}

// Round 5
// 795.151 us; speedup vs baseline: 1.8104x; 1.2329x over previous
//
#include <hip/hip_runtime.h>

typedef __attribute__((ext_vector_type(4))) float floatx4;
typedef __attribute__((ext_vector_type(8))) short bf16x8;

#define NPB 256      /* nodes per bucket; bucket = dst >> 8 */
#define CHUNK 6144   /* edges per partition workgroup */
#define MAXB 12288   /* fine-sort LDS cap (avg bucket = 8184 for E=3.2M) */

__device__ __forceinline__ float bf2f(unsigned short h) {
  union { unsigned int u; float f; } c; c.u = ((unsigned int)h) << 16; return c.f;
}
__device__ __forceinline__ unsigned short f2bf(float f) {
  union { float f; unsigned int u; } c; c.f = f;
  unsigned int r = c.u + 0x7FFFu + ((c.u >> 16) & 1u);
  return (unsigned short)(r >> 16);
}

// ---------------- bucketed CSR build (all writes coalesced) ----------------

__global__ __launch_bounds__(256) void bhist_k(const int* __restrict__ dst,
                                               int* __restrict__ bcnt, int E, int B) {
  __shared__ int h[512];
  int tid = threadIdx.x;
  for (int i = tid; i < 512; i += 256) h[i] = 0;
  __syncthreads();
  for (int i = blockIdx.x * 256 + tid; i < E; i += gridDim.x * 256)
    atomicAdd(&h[dst[i] >> 8], 1);
  __syncthreads();
  for (int i = tid; i < B; i += 256)
    if (h[i]) atomicAdd(&bcnt[i], h[i]);
}

__global__ __launch_bounds__(512) void bscan_k(const int* __restrict__ bcnt,
                                               int* __restrict__ bstart,
                                               int* __restrict__ bcur, int B) {
  __shared__ int s[512];
  int tid = threadIdx.x;
  int v = (tid < B) ? bcnt[tid] : 0;
  s[tid] = v;
  __syncthreads();
  for (int off = 1; off < 512; off <<= 1) {
    int t = (tid >= off) ? s[tid - off] : 0;
    __syncthreads();
    s[tid] += t;
    __syncthreads();
  }
  int excl = s[tid] - v;
  if (tid < B) { bstart[tid] = excl; bcur[tid] = excl; }
  if (tid == 511) bstart[B] = s[511];
}

// partition edges into bucket-grouped 8B records {src|w15<<17, local_d}
__global__ __launch_bounds__(256) void part_k(const int* __restrict__ src,
                                              const int* __restrict__ dst,
                                              const float* __restrict__ w,
                                              int* __restrict__ bcur,
                                              int2* __restrict__ prec, int E, int B) {
  __shared__ int hist[512];
  __shared__ int lstart[512];
  __shared__ int cur[512];
  __shared__ int gbase[512];
  __shared__ int ss[256];
  __shared__ int2 srt[CHUNK];
  int tid = threadIdx.x;
  int e0 = blockIdx.x * CHUNK;
  int cnt = min(CHUNK, E - e0);
  for (int i = tid; i < 512; i += 256) hist[i] = 0;
  __syncthreads();
  for (int i = tid; i < cnt; i += 256) atomicAdd(&hist[dst[e0 + i] >> 8], 1);
  __syncthreads();
  // exclusive scan over 512 bins (2 per thread)
  int a0 = hist[2 * tid], a1 = hist[2 * tid + 1];
  ss[tid] = a0 + a1;
  __syncthreads();
  for (int off = 1; off < 256; off <<= 1) {
    int t = (tid >= off) ? ss[tid - off] : 0;
    __syncthreads();
    ss[tid] += t;
    __syncthreads();
  }
  int excl = tid ? ss[tid - 1] : 0;
  lstart[2 * tid] = excl;     cur[2 * tid] = excl;
  lstart[2 * tid + 1] = excl + a0; cur[2 * tid + 1] = excl + a0;
  __syncthreads();
  for (int i = tid; i < B; i += 256)
    gbase[i] = hist[i] ? atomicAdd(&bcur[i], hist[i]) : 0;
  __syncthreads();
  for (int i = tid; i < cnt; i += 256) {
    int d = dst[e0 + i];
    int b = d >> 8;
    float wf = w[e0 + i];
    int w15 = (int)(wf * 32768.f + 0.5f);
    if (w15 > 32767) w15 = 32767;
    int2 r;
    r.x = src[e0 + i] | (w15 << 17);
    r.y = (b << 8) | (d & 255);
    int pos = atomicAdd(&cur[b], 1);
    srt[pos] = r;
  }
  __syncthreads();
  for (int j = tid; j < cnt; j += 256) {
    int2 r = srt[j];
    int b = r.y >> 8;
    prec[gbase[b] + (j - lstart[b])] = make_int2(r.x, r.y & 255);
  }
}

// per-bucket counting sort by local node id; emits row_start/counts + 4B recs
__global__ __launch_bounds__(256) void sort_k(const int2* __restrict__ prec,
                                              const int* __restrict__ bstart,
                                              unsigned int* __restrict__ recs,
                                              int* __restrict__ row_start,
                                              int* __restrict__ counts, int N, int B) {
  __shared__ int hist[256], lstart[256], cur[256], ss[256];
  __shared__ unsigned int srt[MAXB];
  int b = blockIdx.x;
  int tid = threadIdx.x;
  int s = bstart[b];
  int cnt = bstart[b + 1] - s;
  if (cnt > MAXB) cnt = MAXB;  // safety (cannot trigger for uniform dst)
  hist[tid] = 0;
  __syncthreads();
  for (int i = tid; i < cnt; i += 256) atomicAdd(&hist[prec[s + i].y], 1);
  __syncthreads();
  ss[tid] = hist[tid];
  __syncthreads();
  for (int off = 1; off < 256; off <<= 1) {
    int t = (tid >= off) ? ss[tid - off] : 0;
    __syncthreads();
    ss[tid] += t;
    __syncthreads();
  }
  int excl = ss[tid] - hist[tid];
  lstart[tid] = excl;
  cur[tid] = excl;
  int node = b * NPB + tid;
  if (node < N) { row_start[node] = s + excl; counts[node] = hist[tid]; }
  __syncthreads();
  for (int i = tid; i < cnt; i += 256) {
    int2 r = prec[s + i];
    int pos = atomicAdd(&cur[r.y], 1);
    srt[pos] = (unsigned int)r.x;
  }
  __syncthreads();
  for (int i = tid; i < cnt; i += 256) recs[s + i] = srt[i];
}

// ---------------- W1 transpose + bf16 convert: [512,128]f32 -> [128,512]bf16

__global__ __launch_bounds__(256) void tw1_k(const float* __restrict__ W1,
                                             unsigned short* __restrict__ W1t) {
  int i = blockIdx.x * 256 + threadIdx.x;
  if (i >= 512 * 128) return;
  int k = i >> 7, n = i & 127;
  W1t[n * 512 + k] = f2bf(W1[i]);
}

// ---------------- layer-1 GEMM via MFMA --------------------------------

__global__ __launch_bounds__(256) void gemm1_mfma(const float* __restrict__ A,
                                                  const unsigned short* __restrict__ W1t,
                                                  unsigned short* __restrict__ C, int N) {
  constexpr int K = 512, BK = 64, PAD = 72;
  __shared__ short As[128 * PAD];
  __shared__ short Bs[128 * PAD];
  int tid = threadIdx.x;
  int lane = tid & 63;
  int w = tid >> 6;
  int m0 = lane & 15;
  int kq = lane >> 4;
  int rowBase = blockIdx.x * 128;

  floatx4 acc[8][2];
#pragma unroll
  for (int i = 0; i < 8; ++i)
#pragma unroll
    for (int j = 0; j < 2; ++j) acc[i][j] = (floatx4)0.f;

  for (int k0 = 0; k0 < K; k0 += BK) {
#pragma unroll
    for (int it = 0; it < 8; ++it) {
      int f = (tid + it * 256) * 4;
      int r = f >> 6;
      int kk = f & 63;
      int gr = rowBase + r;
      float4 v = make_float4(0.f, 0.f, 0.f, 0.f);
      if (gr < N) v = *reinterpret_cast<const float4*>(&A[(size_t)gr * K + k0 + kk]);
      unsigned int u0 = ((unsigned int)f2bf(v.y) << 16) | f2bf(v.x);
      unsigned int u1 = ((unsigned int)f2bf(v.w) << 16) | f2bf(v.z);
      *reinterpret_cast<uint2*>(&As[r * PAD + kk]) = make_uint2(u0, u1);
    }
#pragma unroll
    for (int it = 0; it < 4; ++it) {
      int t2 = tid + it * 256;
      int n = t2 >> 3;
      int kc = (t2 & 7) * 8;
      uint4 v = *reinterpret_cast<const uint4*>(&W1t[(size_t)n * 512 + k0 + kc]);
      *reinterpret_cast<uint4*>(&Bs[n * PAD + kc]) = v;
    }
    __syncthreads();
#pragma unroll
    for (int kb = 0; kb < 2; ++kb) {
      int kbase = kb * 32 + kq * 8;
      bf16x8 a[8], bb[2];
#pragma unroll
      for (int mi = 0; mi < 8; ++mi)
        a[mi] = *reinterpret_cast<const bf16x8*>(&As[(mi * 16 + m0) * PAD + kbase]);
#pragma unroll
      for (int jn = 0; jn < 2; ++jn)
        bb[jn] = *reinterpret_cast<const bf16x8*>(&Bs[(w * 32 + jn * 16 + m0) * PAD + kbase]);
#pragma unroll
      for (int mi = 0; mi < 8; ++mi)
#pragma unroll
        for (int jn = 0; jn < 2; ++jn)
          acc[mi][jn] = __builtin_amdgcn_mfma_f32_16x16x32_bf16(a[mi], bb[jn], acc[mi][jn], 0, 0, 0);
    }
    __syncthreads();
  }
#pragma unroll
  for (int mi = 0; mi < 8; ++mi) {
#pragma unroll
    for (int jn = 0; jn < 2; ++jn) {
      int gc = w * 32 + jn * 16 + m0;
#pragma unroll
      for (int p = 0; p < 4; ++p) {
        int gr = rowBase + mi * 16 + kq * 4 + p;
        if (gr < N) C[(size_t)gr * 128 + gc] = f2bf(acc[mi][jn][p]);
      }
    }
  }
}

// ---------------- small GEMM (layers 2-4): bf16 A, fp32 W -> bf16 --------

template <int K, int O>
__global__ __launch_bounds__(256) void gemm_kernel(const unsigned short* __restrict__ A,
                                                   const float* __restrict__ W,
                                                   unsigned short* __restrict__ C, int N) {
  constexpr int BM = 64;
  constexpr int BK = 32;
  constexpr int TM = 4;
  constexpr int TN = O / 16;
  __shared__ float As[BK][BM];
  __shared__ float Ws[BK][O];
  int tid = threadIdx.x;
  int tx = tid % 16;
  int ty = tid / 16;
  int rowBase = blockIdx.x * BM;
  float acc[TM][TN];
#pragma unroll
  for (int i = 0; i < TM; ++i)
#pragma unroll
    for (int j = 0; j < TN; ++j) acc[i][j] = 0.f;

  for (int k0 = 0; k0 < K; k0 += BK) {
    {
      int r = tid >> 2;
      int kc = (tid & 3) * 8;
      int gr = rowBase + r;
      uint4 v = make_uint4(0u, 0u, 0u, 0u);
      if (gr < N) v = *reinterpret_cast<const uint4*>(&A[(size_t)gr * K + k0 + kc]);
      const unsigned short* pv = reinterpret_cast<const unsigned short*>(&v);
#pragma unroll
      for (int j = 0; j < 8; ++j) As[kc + j][r] = bf2f(pv[j]);
    }
    {
      constexpr int ELEMS = BK * O / 256;
      constexpr int NV = ELEMS / 4;
#pragma unroll
      for (int it = 0; it < NV; ++it) {
        int linear = (tid + it * 256) * 4;
        int kk = linear / O;
        int oo = linear % O;
        float4 v = *reinterpret_cast<const float4*>(&W[(size_t)(k0 + kk) * O + oo]);
        Ws[kk][oo + 0] = v.x; Ws[kk][oo + 1] = v.y;
        Ws[kk][oo + 2] = v.z; Ws[kk][oo + 3] = v.w;
      }
    }
    __syncthreads();
#pragma unroll
    for (int k = 0; k < BK; ++k) {
      float a[TM], w[TN];
#pragma unroll
      for (int i = 0; i < TM; ++i) a[i] = As[k][ty * TM + i];
#pragma unroll
      for (int j = 0; j < TN; ++j) w[j] = Ws[k][tx * TN + j];
#pragma unroll
      for (int i = 0; i < TM; ++i)
#pragma unroll
        for (int j = 0; j < TN; ++j) acc[i][j] += a[i] * w[j];
    }
    __syncthreads();
  }
#pragma unroll
  for (int i = 0; i < TM; ++i) {
    int gr = rowBase + ty * TM + i;
    if (gr >= N) continue;
#pragma unroll
    for (int j = 0; j < TN; j += 2) {
      unsigned int p = ((unsigned int)f2bf(acc[i][j + 1]) << 16) | f2bf(acc[i][j]);
      *reinterpret_cast<unsigned int*>(&C[(size_t)gr * O + tx * TN + j]) = p;
    }
  }
}

// ---------------- SpMM (CSR by dst, register accumulate, 8x MLP) ---------
// rec: src = v & 0x1FFFF, w = (v>>17) / 32768

#define INV32768 3.0517578125e-05f

template <int O, bool RELU>
__global__ __launch_bounds__(256) void spmm_kernel(const unsigned int* __restrict__ recs,
                                                   const int* __restrict__ row_start,
                                                   const int* __restrict__ counts,
                                                   const unsigned short* __restrict__ sup,
                                                   unsigned short* __restrict__ hout, int N) {
  constexpr int SUBW = O / 2;
  constexpr int NPW = 256 / SUBW;
  constexpr int U = 8;
  int tid = threadIdx.x;
  int lane = tid % SUBW;
  int sub = tid / SUBW;
  int node = blockIdx.x * NPW + sub;
  if (node >= N) return;
  int start = row_start[node];
  int deg = counts[node];
  const unsigned int* supu = reinterpret_cast<const unsigned int*>(sup);
  const unsigned int* rp = recs + start;
  float a0 = 0.f, a1 = 0.f;
  int i = 0;
  for (; i + U <= deg; i += U) {
    unsigned int r[U];
#pragma unroll
    for (int j = 0; j < U; ++j) r[j] = rp[i + j];
    unsigned int v[U];
#pragma unroll
    for (int j = 0; j < U; ++j) v[j] = supu[(size_t)(r[j] & 0x1FFFFu) * (O / 2) + lane];
#pragma unroll
    for (int j = 0; j < U; ++j) {
      float w = (float)(r[j] >> 17) * INV32768;
      a0 += w * bf2f((unsigned short)(v[j] & 0xFFFFu));
      a1 += w * bf2f((unsigned short)(v[j] >> 16));
    }
  }
  for (; i < deg; ++i) {
    unsigned int rec = rp[i];
    float w = (float)(rec >> 17) * INV32768;
    unsigned int v = supu[(size_t)(rec & 0x1FFFFu) * (O / 2) + lane];
    a0 += w * bf2f((unsigned short)(v & 0xFFFFu));
    a1 += w * bf2f((unsigned short)(v >> 16));
  }
  if (RELU) { a0 = fmaxf(a0, 0.f); a1 = fmaxf(a1, 0.f); }
  unsigned int p = ((unsigned int)f2bf(a1) << 16) | f2bf(a0);
  reinterpret_cast<unsigned int*>(hout)[(size_t)node * (O / 2) + lane] = p;
}

__global__ __launch_bounds__(256) void spmm_mulv_kernel(const unsigned int* __restrict__ recs,
                                                        const int* __restrict__ row_start,
                                                        const int* __restrict__ counts,
                                                        const unsigned short* __restrict__ sup,
                                                        float* __restrict__ out, int N) {
  constexpr int SUBW = 16;
  constexpr int NPW = 256 / SUBW;
  constexpr int U = 8;
  int tid = threadIdx.x;
  int lane = tid % SUBW;
  int sub = tid / SUBW;
  int node = blockIdx.x * NPW + sub;
  if (node >= N) return;
  int start = row_start[node];
  int deg = counts[node];
  const unsigned int* supu = reinterpret_cast<const unsigned int*>(sup);
  const unsigned int* rp = recs + start;
  float a0 = 0.f, a1 = 0.f;
  int i = 0;
  for (; i + U <= deg; i += U) {
    unsigned int r[U];
#pragma unroll
    for (int j = 0; j < U; ++j) r[j] = rp[i + j];
    unsigned int v[U];
#pragma unroll
    for (int j = 0; j < U; ++j) v[j] = supu[(size_t)(r[j] & 0x1FFFFu) * 16 + lane];
#pragma unroll
    for (int j = 0; j < U; ++j) {
      float w = (float)(r[j] >> 17) * INV32768;
      a0 += w * bf2f((unsigned short)(v[j] & 0xFFFFu));
      a1 += w * bf2f((unsigned short)(v[j] >> 16));
    }
  }
  for (; i < deg; ++i) {
    unsigned int rec = rp[i];
    float w = (float)(rec >> 17) * INV32768;
    unsigned int v = supu[(size_t)(rec & 0x1FFFFu) * 16 + lane];
    a0 += w * bf2f((unsigned short)(v & 0xFFFFu));
    a1 += w * bf2f((unsigned short)(v >> 16));
  }
  size_t nf = (size_t)N * 16;
  if (lane < 8) {
    float2 p = make_float2(a0, a1);
    *reinterpret_cast<float2*>(&out[(size_t)node * 16 + lane * 2]) = p;
    *reinterpret_cast<float2*>(&out[nf + (size_t)node * 16 + lane * 2]) = p;
  } else {
    int l = lane - 8;
    *reinterpret_cast<float2*>(&out[2 * nf + (size_t)node * 16 + l * 2]) =
        make_float2(a0, a1);
  }
}

__global__ void packw_k(const float* __restrict__ Wmu,
                        const float* __restrict__ Wlv,
                        float* __restrict__ Wcat) {
  int i = blockIdx.x * 256 + threadIdx.x;
  if (i >= 32 * 32) return;
  int k = i / 32, o = i % 32;
  Wcat[i] = (o < 16) ? Wmu[k * 16 + o] : Wlv[k * 16 + (o - 16)];
}

// ---------------- launch ----------------

extern "C" void kernel_launch(void* const* d_in, const int* in_sizes, int n_in,
                              void* d_out, int out_size, void* d_ws, size_t ws_size,
                              hipStream_t stream) {
  const float* x    = (const float*)d_in[0];
  const int* esrc   = (const int*)d_in[1];
  const int* edst   = (const int*)d_in[2];
  const float* ew   = (const float*)d_in[3];
  const float* W1   = (const float*)d_in[4];
  const float* W2   = (const float*)d_in[5];
  const float* W3   = (const float*)d_in[6];
  const float* Wmu  = (const float*)d_in[7];
  const float* Wlv  = (const float*)d_in[8];
  float* out = (float*)d_out;
  int N = in_sizes[0] / 512;
  int E = in_sizes[1];
  int B = (N + NPB - 1) / NPB;

  char* p = (char*)d_ws;
  auto alloc = [&](size_t bytes) -> char* {
    char* r = p;
    p += (bytes + 255) & ~(size_t)255;
    return r;
  };
  int*  counts = (int*)alloc((size_t)N * 4);
  int*  rowst  = (int*)alloc((size_t)N * 4);
  int*  bcnt   = (int*)alloc((size_t)(B + 1) * 4);
  int*  bstart = (int*)alloc((size_t)(B + 1) * 4);
  int*  bcur   = (int*)alloc((size_t)(B + 1) * 4);
  int2* prec   = (int2*)alloc((size_t)E * 8);
  unsigned int* recs = (unsigned int*)alloc((size_t)E * 4);
  unsigned short* bufA = (unsigned short*)alloc((size_t)N * 128 * 2);
  unsigned short* bufB = (unsigned short*)alloc((size_t)N * 128 * 2);
  unsigned short* W1t  = (unsigned short*)alloc(512 * 128 * 2);
  float* Wcat = (float*)alloc(32 * 32 * 4);

  // CSR build: bucket hist -> scan -> LDS-binned partition -> per-bucket sort
  hipMemsetAsync(bcnt, 0, (size_t)(B + 1) * 4, stream);
  bhist_k<<<256, 256, 0, stream>>>(edst, bcnt, E, B);
  bscan_k<<<1, 512, 0, stream>>>(bcnt, bstart, bcur, B);
  part_k<<<(E + CHUNK - 1) / CHUNK, 256, 0, stream>>>(esrc, edst, ew, bcur, prec, E, B);
  sort_k<<<B, 256, 0, stream>>>(prec, bstart, recs, rowst, counts, N, B);

  // layer 1: MFMA GEMM [N,512](f32->bf16) @ W1 -> spmm(relu) -> h1 in bufB
  tw1_k<<<256, 256, 0, stream>>>(W1, W1t);
  gemm1_mfma<<<(N + 127) / 128, 256, 0, stream>>>(x, W1t, bufA, N);
  spmm_kernel<128, true><<<(N + 3) / 4, 256, 0, stream>>>(recs, rowst, counts, bufA, bufB, N);

  int gemmGrid = (N + 63) / 64;

  // layer 2: [N,128]@[128,64] -> spmm(relu) -> h2 in bufB
  gemm_kernel<128, 64><<<gemmGrid, 256, 0, stream>>>(bufB, W2, bufA, N);
  spmm_kernel<64, true><<<(N + 7) / 8, 256, 0, stream>>>(recs, rowst, counts, bufA, bufB, N);

  // layer 3: [N,64]@[64,32] -> spmm(relu) -> h3 in bufB
  gemm_kernel<64, 32><<<gemmGrid, 256, 0, stream>>>(bufB, W3, bufA, N);
  spmm_kernel<32, true><<<(N + 15) / 16, 256, 0, stream>>>(recs, rowst, counts, bufA, bufB, N);

  // final: [N,32] @ [32,32(cat mu|lv)] -> spmm -> (z, mu, logvar) fp32
  packw_k<<<4, 256, 0, stream>>>(Wmu, Wlv, Wcat);
  gemm_kernel<32, 32><<<gemmGrid, 256, 0, stream>>>(bufB, Wcat, bufA, N);
  spmm_mulv_kernel<<<(N + 15) / 16, 256, 0, stream>>>(recs, rowst, counts, bufA, out, N);
}